// Round 6
// baseline (115.846 us; speedup 1.0000x reference)
//
#include <hip/hip_runtime.h>
#include <math.h>

#define BATCH 4
#define SEQ   1024
#define DIN   512
#define DKQ   512
#define DV    64
#define NH    64

typedef __attribute__((ext_vector_type(8))) short short8v;   // 8 bf16 = 4 VGPRs
typedef __attribute__((ext_vector_type(4))) float float4v;
typedef __attribute__((ext_vector_type(4))) unsigned int uint4v;

__device__ __forceinline__ void split_bf16(float f, unsigned short& hi, unsigned short& lo) {
    unsigned int u = __float_as_uint(f);
    hi = (unsigned short)(u >> 16);
    float l = f - __uint_as_float(u & 0xFFFF0000u);
    lo = (unsigned short)(__float_as_uint(l) >> 16);
}
__device__ __forceinline__ unsigned short f32_to_bf16_rne(float f) {
    unsigned int u = __float_as_uint(f);
    u += 0x7FFFu + ((u >> 16) & 1u);
    return (unsigned short)(u >> 16);
}
__device__ __forceinline__ float bf16_bits_to_f32(unsigned short s) {
    return __uint_as_float((unsigned int)s << 16);
}

// ---------------------------------------------------------------------------
// x pre-pack: f32 -> bf16 hi/lo planes. Also writes the ones/zeros const
// block used by attn's V-fragment gather.
// ---------------------------------------------------------------------------
__global__ __launch_bounds__(256)
void pack_x(const float* __restrict__ x,
            unsigned short* __restrict__ Xhi, unsigned short* __restrict__ Xlo,
            unsigned int* __restrict__ obuf)
{
    if (blockIdx.x == 0 && threadIdx.x < 8)
        obuf[threadIdx.x] = (threadIdx.x < 4) ? 0x3F803F80u : 0u;
    const int i = (blockIdx.x * 256 + threadIdx.x) * 8;
    float4 a0 = *(const float4*)&x[i];
    float4 a1 = *(const float4*)&x[i + 4];
    float av[8] = {a0.x, a0.y, a0.z, a0.w, a1.x, a1.y, a1.z, a1.w};
    short8v h, l;
    #pragma unroll
    for (int j = 0; j < 8; ++j) {
        unsigned short hh, ll; split_bf16(av[j], hh, ll);
        h[j] = (short)hh; l[j] = (short)ll;
    }
    *(short8v*)&Xhi[i] = h;
    *(short8v*)&Xlo[i] = l;
}

// ---------------------------------------------------------------------------
// W transpose + pack pre-pass: Whi/Wlo[n][k] = bf16 hi/lo of W[k][n]
// ---------------------------------------------------------------------------
__global__ __launch_bounds__(256)
void transpose_w(const float* __restrict__ Wq, const float* __restrict__ Wk,
                 const float* __restrict__ Wv,
                 unsigned short* __restrict__ WhiQ, unsigned short* __restrict__ WloQ,
                 unsigned short* __restrict__ WhiK, unsigned short* __restrict__ WloK,
                 unsigned short* __restrict__ WhiV, unsigned short* __restrict__ WloV)
{
    const int z = blockIdx.z;
    const int N = (z == 2) ? DV : DKQ;
    if (z == 2 && blockIdx.x >= 2) return;
    const float* __restrict__ W = (z == 0) ? Wq : (z == 1) ? Wk : Wv;
    unsigned short* __restrict__ Whi = (z == 0) ? WhiQ : (z == 1) ? WhiK : WhiV;
    unsigned short* __restrict__ Wlo = (z == 0) ? WloQ : (z == 1) ? WloK : WloV;

    __shared__ float tile[32][33];
    const int n0 = blockIdx.x * 32, k0 = blockIdx.y * 32;
    const int tx = threadIdx.x, ty = threadIdx.y;
    #pragma unroll
    for (int i = 0; i < 32; i += 8)
        tile[ty + i][tx] = W[(size_t)(k0 + ty + i) * N + n0 + tx];
    __syncthreads();
    #pragma unroll
    for (int i = 0; i < 32; i += 8) {
        unsigned short h, l; split_bf16(tile[tx][ty + i], h, l);
        Whi[(size_t)(n0 + ty + i) * DIN + k0 + tx] = h;
        Wlo[(size_t)(n0 + ty + i) * DIN + k0 + tx] = l;
    }
}

// ---------------------------------------------------------------------------
// Projection: NO LDS. MFMA fragments are direct b128 global loads from the
// pre-packed [row][k] planes (L1/L2-served gather; every 64B line fully
// used). Wave tile 64x64 (4mt x 4nf), 3-term hi/lo compensation, depth-1
// ping-pong prefetch, zero barriers. 4 waves/block.
//   z=0: Q -> Qpk[bh][s][0..7]=hi,[8..15]=lo (pre-scaled by 1/sqrt(8)*log2e)
//   z=1: K -> Kpk same layout
//   z=2: V -> Vsh/Vsl: superstep-fragment-major u32 planes (see idx math)
// Grid (2, 64, 3): z0/z1: block = 64 rows x 256 cols (waves side by side);
// z2: x==0, y<16: block = 256 rows x 64 cols (waves stacked in M).
// ---------------------------------------------------------------------------
__global__ __launch_bounds__(256)
void proj_kernel(const unsigned short* __restrict__ Xhi,
                 const unsigned short* __restrict__ Xlo,
                 const unsigned short* __restrict__ WhiQ, const unsigned short* __restrict__ WloQ,
                 const float* __restrict__ bq,
                 const unsigned short* __restrict__ WhiK, const unsigned short* __restrict__ WloK,
                 const float* __restrict__ bk,
                 const unsigned short* __restrict__ WhiV, const unsigned short* __restrict__ WloV,
                 const float* __restrict__ bv,
                 unsigned short* __restrict__ Qpk, unsigned short* __restrict__ Kpk,
                 unsigned int* __restrict__ Vsh, unsigned int* __restrict__ Vsl)
{
    const int z = blockIdx.z;
    const int t = threadIdx.x;
    const int wave = t >> 6, lane = t & 63;
    const int cl = lane & 15, g2 = lane >> 4;

    int bm, cb;
    if (z == 2) {
        if (blockIdx.x != 0 || blockIdx.y >= 16) return;
        bm = blockIdx.y * 256 + wave * 64;
        cb = 0;
    } else {
        bm = blockIdx.y * 64;
        cb = blockIdx.x * 256 + wave * 64;
    }
    const unsigned short* __restrict__ Whi = (z == 0) ? WhiQ : (z == 1) ? WhiK : WhiV;
    const unsigned short* __restrict__ Wlo = (z == 0) ? WloQ : (z == 1) ? WloK : WloV;
    const float* __restrict__ bias = (z == 0) ? bq : (z == 1) ? bk : bv;

    unsigned int aoff[4], boff[4];
    #pragma unroll
    for (int mt = 0; mt < 4; ++mt) aoff[mt] = (unsigned)(bm + mt * 16 + cl) * DIN + g2 * 8;
    #pragma unroll
    for (int nf = 0; nf < 4; ++nf) boff[nf] = (unsigned)(cb + nf * 16 + cl) * DIN + g2 * 8;

    float4v acc[4][4];
    #pragma unroll
    for (int i = 0; i < 4; ++i)
        #pragma unroll
        for (int j = 0; j < 4; ++j)
            acc[i][j] = (float4v){0.f, 0.f, 0.f, 0.f};

    short8v Ah[2][4], Al[2][4], Bh[2][4], Bl[4];
    #pragma unroll
    for (int mt = 0; mt < 4; ++mt) {
        Ah[0][mt] = *(const short8v*)(Xhi + aoff[mt]);
        Al[0][mt] = *(const short8v*)(Xlo + aoff[mt]);
    }
    #pragma unroll
    for (int nf = 0; nf < 4; ++nf)
        Bh[0][nf] = *(const short8v*)(Whi + boff[nf]);

    #pragma unroll
    for (int ks = 0; ks < 16; ++ks) {
        const int cur = ks & 1, nxt = cur ^ 1;
        const int ko = ks * 32;
        // lo-plane B for current ks (consumed by the 3rd term group below)
        #pragma unroll
        for (int nf = 0; nf < 4; ++nf)
            Bl[nf] = *(const short8v*)(Wlo + boff[nf] + ko);
        // prefetch next ks
        if (ks < 15) {
            const int kn = ko + 32;
            #pragma unroll
            for (int mt = 0; mt < 4; ++mt) {
                Ah[nxt][mt] = *(const short8v*)(Xhi + aoff[mt] + kn);
                Al[nxt][mt] = *(const short8v*)(Xlo + aoff[mt] + kn);
            }
            #pragma unroll
            for (int nf = 0; nf < 4; ++nf)
                Bh[nxt][nf] = *(const short8v*)(Whi + boff[nf] + kn);
        }
        #pragma unroll
        for (int mt = 0; mt < 4; ++mt)
            #pragma unroll
            for (int nf = 0; nf < 4; ++nf)
                acc[mt][nf] = __builtin_amdgcn_mfma_f32_16x16x32_bf16(Ah[cur][mt], Bh[cur][nf], acc[mt][nf], 0, 0, 0);
        #pragma unroll
        for (int mt = 0; mt < 4; ++mt)
            #pragma unroll
            for (int nf = 0; nf < 4; ++nf)
                acc[mt][nf] = __builtin_amdgcn_mfma_f32_16x16x32_bf16(Al[cur][mt], Bh[cur][nf], acc[mt][nf], 0, 0, 0);
        #pragma unroll
        for (int mt = 0; mt < 4; ++mt)
            #pragma unroll
            for (int nf = 0; nf < 4; ++nf)
                acc[mt][nf] = __builtin_amdgcn_mfma_f32_16x16x32_bf16(Ah[cur][mt], Bl[nf], acc[mt][nf], 0, 0, 0);
    }

    const float cc = 0.35355339059327373f * 1.4426950408889634f;
    if (z == 2) {
        #pragma unroll
        for (int mt = 0; mt < 4; ++mt) {
            const int row0 = bm + mt * 16 + g2 * 4;
            const int bb = row0 >> 10, s0 = row0 & 1023;
            // fragment-major u32 index: idx(s) = (s>>5)*16 + ((s>>2)&3)*4
            //                                    + ((s>>4)&1)*2 + ((s>>1)&1)
            const int idx0 = (s0 >> 5) * 16 + ((s0 >> 2) & 3) * 4 + ((s0 >> 4) & 1) * 2;
            #pragma unroll
            for (int nf = 0; nf < 4; ++nf) {
                const int n = nf * 16 + cl;   // head
                const float bn = bias[n];
                float vv[4]; unsigned short hh[4], ll[4];
                #pragma unroll
                for (int r = 0; r < 4; ++r) {
                    vv[r] = fmaxf(acc[mt][nf][r] + bn, 0.0f);
                    hh[r] = f32_to_bf16_rne(vv[r]);
                    ll[r] = f32_to_bf16_rne(vv[r] - bf16_bits_to_f32(hh[r]));
                }
                const size_t base = (size_t)((bb << 6) + n) * 512 + idx0;
                Vsh[base]     = (unsigned int)hh[0] | ((unsigned int)hh[1] << 16);
                Vsh[base + 1] = (unsigned int)hh[2] | ((unsigned int)hh[3] << 16);
                Vsl[base]     = (unsigned int)ll[0] | ((unsigned int)ll[1] << 16);
                Vsl[base + 1] = (unsigned int)ll[2] | ((unsigned int)ll[3] << 16);
            }
        }
    } else {
        unsigned short* __restrict__ dst = (z == 0) ? Qpk : Kpk;
        #pragma unroll
        for (int nf = 0; nf < 4; ++nf) {
            const int n = cb + nf * 16 + cl;
            const float bn = bias[n];
            const int h = n >> 3, d = n & 7;
            #pragma unroll
            for (int mt = 0; mt < 4; ++mt) {
                #pragma unroll
                for (int r = 0; r < 4; ++r) {
                    const int row = bm + mt * 16 + g2 * 4 + r;
                    const int bb = row >> 10, s = row & 1023;
                    float val = fmaxf(acc[mt][nf][r] + bn, 0.0f);
                    if (z == 0) val *= cc;
                    const size_t base = ((size_t)((bb << 6) + h) * SEQ + s) * 16 + d;
                    unsigned short hi = f32_to_bf16_rne(val);
                    dst[base]     = hi;
                    dst[base + 8] = f32_to_bf16_rne(val - bf16_bits_to_f32(hi));
                }
            }
        }
    }
}

// ---------------------------------------------------------------------------
// Attention, swapped-operand + superstep-2: per superstep (32 keys) do
// 8 QK^T MFMAs (4 qt x 2 tiles) and 4 PV MFMAs with the FULL K=32
// (slots 0-3 = tile0 p, 4-7 = tile1 p). V A-fragment comes from ONE b128
// gather (per-lane pointer: v_hi / ones / v_lo / zeros, selected once,
// stride-incremented). Split-K 4-way, partials to ws.
// ---------------------------------------------------------------------------
__global__ __launch_bounds__(256, 4)
void attn_kernel(const unsigned short* __restrict__ Qpk,
                 const unsigned short* __restrict__ Kpk,
                 const unsigned int* __restrict__ Vsh,
                 const unsigned int* __restrict__ Vsl,
                 const unsigned int* __restrict__ obuf,
                 float2* __restrict__ part)
{
    const int bh = blockIdx.x;          // b*64 + h
    const int yb = blockIdx.y;          // 0..15
    const int qchunk = yb >> 2;         // 0..3
    const int kq = yb & 3;              // key quarter
    const int t = threadIdx.x;
    const int wave = t >> 6, lane = t & 63;
    const int g = lane >> 4, cl = lane & 15;

    const unsigned short* __restrict__ qb = Qpk + (size_t)bh * SEQ * 16;
    const unsigned short* __restrict__ kb = Kpk + (size_t)bh * SEQ * 16;

    const int q0 = qchunk * 256 + wave * 64;

    // B(Q) fragments: col=cl=query; k-slot groups g0=hi, g1=lo, g2=hi, g3=0
    short8v bq[4];
    #pragma unroll
    for (int qt = 0; qt < 4; ++qt) {
        if (g == 3) { short8v zz = {0,0,0,0,0,0,0,0}; bq[qt] = zz; }
        else bq[qt] = *(const short8v*)(qb + (size_t)(q0 + qt * 16 + cl) * 16 + ((g == 1) ? 8 : 0));
    }

    // A(K) fragment plane: g0,g1 -> hi; g2,g3 -> lo (g3's B slots are 0)
    const int koff = (g >> 1) * 8;
    const unsigned short* kp = kb + kq * 4096 + cl * 16 + koff;

    // V A-fragment gather pointer (one b128 per superstep)
    const unsigned int* ap;
    int astr;
    {
        const size_t vb = (size_t)bh * 512 + kq * 128 + g * 4;
        if (cl == 0)      { ap = Vsh + vb; astr = 16; }
        else if (cl == 2) { ap = Vsl + vb; astr = 16; }
        else if (cl == 1) { ap = obuf;     astr = 0;  }
        else              { ap = obuf + 4; astr = 0;  }
    }

    const float4v c0 = {0.f, 0.f, 0.f, 0.f};
    float4v acc[4];
    #pragma unroll
    for (int qt = 0; qt < 4; ++qt) acc[qt] = c0;

    short8v k0c = *(const short8v*)kp;
    short8v k1c = *(const short8v*)(kp + 256);
    uint4v  auc = *(const uint4v*)ap;

    #pragma unroll
    for (int ss = 0; ss < 8; ++ss) {
        short8v k0n, k1n; uint4v aun;
        if (ss < 7) {
            k0n = *(const short8v*)(kp + 512);
            k1n = *(const short8v*)(kp + 768);
            aun = *(const uint4v*)(ap + astr);
        }
        kp += 512; ap += astr;
        const short8v af = __builtin_bit_cast(short8v, auc);
        #pragma unroll
        for (int qt = 0; qt < 4; ++qt) {
            float4v s0 = __builtin_amdgcn_mfma_f32_16x16x32_bf16(k0c, bq[qt], c0, 0, 0, 0);
            float4v s1 = __builtin_amdgcn_mfma_f32_16x16x32_bf16(k1c, bq[qt], c0, 0, 0, 0);
            float p00 = __builtin_amdgcn_exp2f(s0[0]);
            float p01 = __builtin_amdgcn_exp2f(s0[1]);
            float p02 = __builtin_amdgcn_exp2f(s0[2]);
            float p03 = __builtin_amdgcn_exp2f(s0[3]);
            float p10 = __builtin_amdgcn_exp2f(s1[0]);
            float p11 = __builtin_amdgcn_exp2f(s1[1]);
            float p12 = __builtin_amdgcn_exp2f(s1[2]);
            float p13 = __builtin_amdgcn_exp2f(s1[3]);
            unsigned int pk0 = __builtin_amdgcn_perm(__float_as_uint(p01), __float_as_uint(p00), 0x07060302u);
            unsigned int pk1 = __builtin_amdgcn_perm(__float_as_uint(p03), __float_as_uint(p02), 0x07060302u);
            unsigned int pk2 = __builtin_amdgcn_perm(__float_as_uint(p11), __float_as_uint(p10), 0x07060302u);
            unsigned int pk3 = __builtin_amdgcn_perm(__float_as_uint(p13), __float_as_uint(p12), 0x07060302u);
            uint4v pu = {pk0, pk1, pk2, pk3};
            acc[qt] = __builtin_amdgcn_mfma_f32_16x16x32_bf16(af, __builtin_bit_cast(short8v, pu), acc[qt], 0, 0, 0);
        }
        if (ss < 7) { k0c = k0n; k1c = k1n; auc = aun; }
    }

    if (g == 0) {
        #pragma unroll
        for (int qt = 0; qt < 4; ++qt) {
            const int row = q0 + qt * 16 + cl;
            float2 pr;
            pr.x = acc[qt][0] + acc[qt][2];   // numerator (v_hi + v_lo parts)
            pr.y = acc[qt][1];                // denominator
            part[(size_t)(kq * 256 + bh) * SEQ + row] = pr;
        }
    }
}

// ---------------------------------------------------------------------------
// Merge split-K quarters + positional embedding. h-fastest coalesced out.
// ---------------------------------------------------------------------------
__global__ __launch_bounds__(256)
void merge_kernel(const float2* __restrict__ part, float* __restrict__ out)
{
    const int tid = blockIdx.x * 256 + threadIdx.x;  // = (b*1024+q)*64+h
    const int h = tid & 63;
    const int q = (tid >> 6) & 1023;
    const int b = tid >> 16;
    const int bh = (b << 6) + h;
    float num = 0.f, den = 0.f;
    #pragma unroll
    for (int kq = 0; kq < 4; ++kq) {
        float2 p = part[(size_t)(kq * 256 + bh) * SEQ + q];
        num += p.x; den += p.y;
    }
    const float fr = __builtin_amdgcn_exp2f((float)(h & 31) * -0.4152410118609203f);
    const float pe = (h < 32) ? cosf((float)q * fr) : sinf((float)q * fr);
    out[tid] = num / den + pe;
}

// ---------------------------------------------------------------------------
extern "C" void kernel_launch(void* const* d_in, const int* in_sizes, int n_in,
                              void* d_out, int out_size, void* d_ws, size_t ws_size,
                              hipStream_t stream)
{
    const float* x  = (const float*)d_in[0];
    const float* Wq = (const float*)d_in[1];
    const float* bq = (const float*)d_in[2];
    const float* Wk = (const float*)d_in[3];
    const float* bk = (const float*)d_in[4];
    const float* Wv = (const float*)d_in[5];
    const float* bv = (const float*)d_in[6];
    float* out = (float*)d_out;

    // ws layout:
    //   Qpk 8.39MB | Kpk 8.39MB | Vsh .52 | Vsl .52 | obuf 256B |
    //   Xhi 4.19MB | Xlo 4.19MB  (part[8MB] aliases Xhi: X dead after proj) |
    //   W planes 2.23MB
    unsigned short* Qpk = (unsigned short*)d_ws;
    unsigned short* Kpk = Qpk + (size_t)BATCH * NH * SEQ * 16;
    unsigned int* Vsh = (unsigned int*)(Kpk + (size_t)BATCH * NH * SEQ * 16);
    unsigned int* Vsl = Vsh + (size_t)BATCH * NH * (SEQ / 2);
    unsigned int* obuf = Vsl + (size_t)BATCH * NH * (SEQ / 2);
    unsigned short* Xhi = (unsigned short*)(obuf + 64);
    unsigned short* Xlo = Xhi + (size_t)BATCH * SEQ * DIN;
    float2* part = (float2*)Xhi;   // aliases X planes
    unsigned short* WhiQ = Xlo + (size_t)BATCH * SEQ * DIN;
    unsigned short* WloQ = WhiQ + (size_t)DIN * DKQ;
    unsigned short* WhiK = WloQ + (size_t)DIN * DKQ;
    unsigned short* WloK = WhiK + (size_t)DIN * DKQ;
    unsigned short* WhiV = WloK + (size_t)DIN * DKQ;
    unsigned short* WloV = WhiV + (size_t)DIN * DV;

    pack_x<<<dim3((BATCH * SEQ * DIN) / (8 * 256)), 256, 0, stream>>>(x, Xhi, Xlo, obuf);
    transpose_w<<<dim3(16, 16, 3), dim3(32, 8), 0, stream>>>(
        Wq, Wk, Wv, WhiQ, WloQ, WhiK, WloK, WhiV, WloV);
    proj_kernel<<<dim3(2, 64, 3), 256, 0, stream>>>(
        Xhi, Xlo, WhiQ, WloQ, bq, WhiK, WloK, bk, WhiV, WloV, bv, Qpk, Kpk, Vsh, Vsl);
    attn_kernel<<<dim3(256, 16), 256, 0, stream>>>(Qpk, Kpk, Vsh, Vsl, obuf, part);
    merge_kernel<<<dim3((BATCH * SEQ * DV) / 256), 256, 0, stream>>>(part, out);
}

// Round 7
// 83.309 us; speedup vs baseline: 1.3906x; 1.3906x over previous
//
#include <hip/hip_runtime.h>
#include <math.h>

#define BATCH 4
#define SEQ   1024
#define DIN   512
#define DKQ   512
#define DV    64
#define NH    64

typedef __attribute__((ext_vector_type(8))) short short8v;   // 8 bf16 = 4 VGPRs
typedef __attribute__((ext_vector_type(4))) float float4v;
typedef __attribute__((ext_vector_type(4))) unsigned int uint4v;

__device__ __forceinline__ void split_bf16(float f, unsigned short& hi, unsigned short& lo) {
    unsigned int u = __float_as_uint(f);
    hi = (unsigned short)(u >> 16);
    float l = f - __uint_as_float(u & 0xFFFF0000u);
    lo = (unsigned short)(__float_as_uint(l) >> 16);
}
__device__ __forceinline__ unsigned short f32_to_bf16_rne(float f) {
    unsigned int u = __float_as_uint(f);
    u += 0x7FFFu + ((u >> 16) & 1u);
    return (unsigned short)(u >> 16);
}
__device__ __forceinline__ float bf16_bits_to_f32(unsigned short s) {
    return __uint_as_float((unsigned int)s << 16);
}

// async global -> LDS, 16B per lane; LDS dest = wave-uniform base + lane*16
__device__ __forceinline__ void gll16(const unsigned short* g, unsigned short* l) {
    __builtin_amdgcn_global_load_lds(
        (const __attribute__((address_space(1))) unsigned int*)(g),
        (__attribute__((address_space(3))) unsigned int*)(l),
        16, 0, 0);
}

// ---------------------------------------------------------------------------
// x pre-pack: f32 -> bf16 hi/lo planes + ones/zeros const block for attn.
// ---------------------------------------------------------------------------
__global__ __launch_bounds__(256)
void pack_x(const float* __restrict__ x,
            unsigned short* __restrict__ Xhi, unsigned short* __restrict__ Xlo,
            unsigned int* __restrict__ obuf)
{
    if (blockIdx.x == 0 && threadIdx.x < 8)
        obuf[threadIdx.x] = (threadIdx.x < 4) ? 0x3F803F80u : 0u;
    const int i = (blockIdx.x * 256 + threadIdx.x) * 8;
    float4 a0 = *(const float4*)&x[i];
    float4 a1 = *(const float4*)&x[i + 4];
    float av[8] = {a0.x, a0.y, a0.z, a0.w, a1.x, a1.y, a1.z, a1.w};
    short8v h, l;
    #pragma unroll
    for (int j = 0; j < 8; ++j) {
        unsigned short hh, ll; split_bf16(av[j], hh, ll);
        h[j] = (short)hh; l[j] = (short)ll;
    }
    *(short8v*)&Xhi[i] = h;
    *(short8v*)&Xlo[i] = l;
}

// ---------------------------------------------------------------------------
// W transpose + pack pre-pass: Whi/Wlo[n][k] = bf16 hi/lo of W[k][n]
// ---------------------------------------------------------------------------
__global__ __launch_bounds__(256)
void transpose_w(const float* __restrict__ Wq, const float* __restrict__ Wk,
                 const float* __restrict__ Wv,
                 unsigned short* __restrict__ WhiQ, unsigned short* __restrict__ WloQ,
                 unsigned short* __restrict__ WhiK, unsigned short* __restrict__ WloK,
                 unsigned short* __restrict__ WhiV, unsigned short* __restrict__ WloV)
{
    const int z = blockIdx.z;
    const int N = (z == 2) ? DV : DKQ;
    if (z == 2 && blockIdx.x >= 2) return;
    const float* __restrict__ W = (z == 0) ? Wq : (z == 1) ? Wk : Wv;
    unsigned short* __restrict__ Whi = (z == 0) ? WhiQ : (z == 1) ? WhiK : WhiV;
    unsigned short* __restrict__ Wlo = (z == 0) ? WloQ : (z == 1) ? WloK : WloV;

    __shared__ float tile[32][33];
    const int n0 = blockIdx.x * 32, k0 = blockIdx.y * 32;
    const int tx = threadIdx.x, ty = threadIdx.y;
    #pragma unroll
    for (int i = 0; i < 32; i += 8)
        tile[ty + i][tx] = W[(size_t)(k0 + ty + i) * N + n0 + tx];
    __syncthreads();
    #pragma unroll
    for (int i = 0; i < 32; i += 8) {
        unsigned short h, l; split_bf16(tile[tx][ty + i], h, l);
        Whi[(size_t)(n0 + ty + i) * DIN + k0 + tx] = h;
        Wlo[(size_t)(n0 + ty + i) * DIN + k0 + tx] = l;
    }
}

// ---------------------------------------------------------------------------
// Projection v3: global_load_lds(16B) staging into FRAGMENT-MAJOR LDS.
// Chunk = 16-row subtile x 32k x 1 plane = 1KB; lane i of the staging wave
// fetches (row=i&15, kgroup=i>>4) so that MFMA ds_read_b128 addresses are
// chunk_base + lane*16 (conflict-free, zero VALU staging). Double-buffered,
// depth-1 prefetch, one barrier per K-step (m97 structure).
// Block: 128 rows x 128 cols (z=2: x128x64), 8 waves (2Mx4N), BK=32.
//   z=0: Q -> Qpk[bh][s][0..7]=hi,[8..15]=lo (pre-scaled by 1/sqrt(8)*log2e)
//   z=1: K -> Kpk same layout
//   z=2: V -> Vsh/Vsl superstep-fragment-major u32 planes (attn gather layout)
// ---------------------------------------------------------------------------
__global__ __launch_bounds__(512)
void proj_kernel(const unsigned short* __restrict__ Xhi,
                 const unsigned short* __restrict__ Xlo,
                 const unsigned short* __restrict__ WhiQ, const unsigned short* __restrict__ WloQ,
                 const float* __restrict__ bq,
                 const unsigned short* __restrict__ WhiK, const unsigned short* __restrict__ WloK,
                 const float* __restrict__ bk,
                 const unsigned short* __restrict__ WhiV, const unsigned short* __restrict__ WloV,
                 const float* __restrict__ bv,
                 unsigned short* __restrict__ Qpk, unsigned short* __restrict__ Kpk,
                 unsigned int* __restrict__ Vsh, unsigned int* __restrict__ Vsl)
{
    const int z = blockIdx.z;
    if (z == 2 && blockIdx.x != 0) return;
    const unsigned short* __restrict__ Whi = (z == 0) ? WhiQ : (z == 1) ? WhiK : WhiV;
    const unsigned short* __restrict__ Wlo = (z == 0) ? WloQ : (z == 1) ? WloK : WloV;
    const float* __restrict__ bias = (z == 0) ? bq : (z == 1) ? bk : bv;

    // 2 buffers x 32KB: chunks 0-7 A-hi, 8-15 A-lo, 16-23 B-hi, 24-31 B-lo
    __shared__ unsigned short LDS[2][16384];

    const int t = threadIdx.x;
    const int wave = t >> 6, lane = t & 63;
    const int cl = lane & 15, g2 = lane >> 4;
    const int bm  = blockIdx.y * 128;
    const int cbb = (z == 2) ? 0 : blockIdx.x * 128;
    const int wr = wave >> 2, wc = wave & 3;   // 2x4 wave grid
    const int NF = (z == 2) ? 1 : 2;

    // staging sources (per lane); advance +32 ushorts per K-step
    const unsigned short* sAh = Xhi + (size_t)(bm + wave * 16 + cl) * DIN + g2 * 8;
    const unsigned short* sAl = Xlo + (size_t)(bm + wave * 16 + cl) * DIN + g2 * 8;
    const bool bvalid = (z != 2) || (wave < 4);
    const size_t bro = (size_t)(cbb + wave * 16 + cl) * DIN + g2 * 8;
    const unsigned short* sBh = Whi + (bvalid ? bro : 0);
    const unsigned short* sBl = Wlo + (bvalid ? bro : 0);

    float4v acc[4][2];
    #pragma unroll
    for (int i = 0; i < 4; ++i)
        #pragma unroll
        for (int j = 0; j < 2; ++j)
            acc[i][j] = (float4v){0.f, 0.f, 0.f, 0.f};

    // prologue: stage K-step 0 into buf 0
    {
        unsigned short* L = &LDS[0][0];
        gll16(sAh, L + (wave) * 512);
        gll16(sAl, L + (wave + 8) * 512);
        if (bvalid) {
            gll16(sBh, L + (wave + 16) * 512);
            gll16(sBl, L + (wave + 24) * 512);
        }
    }
    __syncthreads();

    for (int ks = 0; ks < 16; ++ks) {
        const int cur = ks & 1;
        // prefetch next K-step into the other buffer (drained at the barrier)
        if (ks < 15) {
            const int kn = (ks + 1) * 32;
            unsigned short* L = &LDS[cur ^ 1][0];
            gll16(sAh + kn, L + (wave) * 512);
            gll16(sAl + kn, L + (wave + 8) * 512);
            if (bvalid) {
                gll16(sBh + kn, L + (wave + 16) * 512);
                gll16(sBl + kn, L + (wave + 24) * 512);
            }
        }
        const unsigned short* L = &LDS[cur][0];
        short8v af_h[4], af_l[4], bf_h[2], bf_l[2];
        #pragma unroll
        for (int mt = 0; mt < 4; ++mt) {
            af_h[mt] = *(const short8v*)(L + (wr * 4 + mt) * 512 + lane * 8);
            af_l[mt] = *(const short8v*)(L + (8 + wr * 4 + mt) * 512 + lane * 8);
        }
        #pragma unroll
        for (int nf = 0; nf < 2; ++nf) {
            if (nf < NF) {
                bf_h[nf] = *(const short8v*)(L + (16 + wc * NF + nf) * 512 + lane * 8);
                bf_l[nf] = *(const short8v*)(L + (24 + wc * NF + nf) * 512 + lane * 8);
            }
        }
        #pragma unroll
        for (int mt = 0; mt < 4; ++mt)
            #pragma unroll
            for (int nf = 0; nf < 2; ++nf) {
                if (nf >= NF) continue;
                acc[mt][nf] = __builtin_amdgcn_mfma_f32_16x16x32_bf16(af_h[mt], bf_h[nf], acc[mt][nf], 0, 0, 0);
                acc[mt][nf] = __builtin_amdgcn_mfma_f32_16x16x32_bf16(af_l[mt], bf_h[nf], acc[mt][nf], 0, 0, 0);
                acc[mt][nf] = __builtin_amdgcn_mfma_f32_16x16x32_bf16(af_h[mt], bf_l[nf], acc[mt][nf], 0, 0, 0);
            }
        __syncthreads();   // drains prefetch (vmcnt) + LDS reads before buffer swap
    }

    const float cc = 0.35355339059327373f * 1.4426950408889634f;
    if (z == 2) {
        const int n = wc * 16 + cl;   // head
        const float bn = bias[n];
        #pragma unroll
        for (int mt = 0; mt < 4; ++mt) {
            const int row0 = bm + wr * 64 + mt * 16 + g2 * 4;
            const int bb = row0 >> 10, s0 = row0 & 1023;
            // superstep-fragment-major u32 index (matches attn's gather):
            // idx(s) = (s>>5)*16 + ((s>>2)&3)*4 + ((s>>4)&1)*2 + ((s>>1)&1)
            const int idx0 = (s0 >> 5) * 16 + ((s0 >> 2) & 3) * 4 + ((s0 >> 4) & 1) * 2;
            float vv[4]; unsigned short hh[4], ll[4];
            #pragma unroll
            for (int r = 0; r < 4; ++r) {
                vv[r] = fmaxf(acc[mt][0][r] + bn, 0.0f);
                hh[r] = f32_to_bf16_rne(vv[r]);
                ll[r] = f32_to_bf16_rne(vv[r] - bf16_bits_to_f32(hh[r]));
            }
            const size_t base = (size_t)((bb << 6) + n) * 512 + idx0;
            Vsh[base]     = (unsigned int)hh[0] | ((unsigned int)hh[1] << 16);
            Vsh[base + 1] = (unsigned int)hh[2] | ((unsigned int)hh[3] << 16);
            Vsl[base]     = (unsigned int)ll[0] | ((unsigned int)ll[1] << 16);
            Vsl[base + 1] = (unsigned int)ll[2] | ((unsigned int)ll[3] << 16);
        }
    } else {
        unsigned short* __restrict__ dst = (z == 0) ? Qpk : Kpk;
        #pragma unroll
        for (int nf = 0; nf < 2; ++nf) {
            const int n = cbb + wc * 32 + nf * 16 + cl;
            const float bn = bias[n];
            const int h = n >> 3, d = n & 7;
            #pragma unroll
            for (int mt = 0; mt < 4; ++mt) {
                #pragma unroll
                for (int r = 0; r < 4; ++r) {
                    const int row = bm + wr * 64 + mt * 16 + g2 * 4 + r;
                    const int bb = row >> 10, s = row & 1023;
                    float val = fmaxf(acc[mt][nf][r] + bn, 0.0f);
                    if (z == 0) val *= cc;
                    const size_t base = ((size_t)((bb << 6) + h) * SEQ + s) * 16 + d;
                    unsigned short hi = f32_to_bf16_rne(val);
                    dst[base]     = hi;
                    dst[base + 8] = f32_to_bf16_rne(val - bf16_bits_to_f32(hi));
                }
            }
        }
    }
}

// ---------------------------------------------------------------------------
// Attention (unchanged from R6): swapped-operand QK^T + superstep-2 PV MFMA
// with full K=32 (tile0 in slots 0-3, tile1 in 4-7); V A-fragment from one
// b128 gather (per-lane v_hi/ones/v_lo/zeros pointer). Split-K 4-way.
// ---------------------------------------------------------------------------
__global__ __launch_bounds__(256, 4)
void attn_kernel(const unsigned short* __restrict__ Qpk,
                 const unsigned short* __restrict__ Kpk,
                 const unsigned int* __restrict__ Vsh,
                 const unsigned int* __restrict__ Vsl,
                 const unsigned int* __restrict__ obuf,
                 float2* __restrict__ part)
{
    const int bh = blockIdx.x;          // b*64 + h
    const int yb = blockIdx.y;          // 0..15
    const int qchunk = yb >> 2;         // 0..3
    const int kq = yb & 3;              // key quarter
    const int t = threadIdx.x;
    const int wave = t >> 6, lane = t & 63;
    const int g = lane >> 4, cl = lane & 15;

    const unsigned short* __restrict__ qb = Qpk + (size_t)bh * SEQ * 16;
    const unsigned short* __restrict__ kb = Kpk + (size_t)bh * SEQ * 16;

    const int q0 = qchunk * 256 + wave * 64;

    // B(Q) fragments: col=cl=query; k-slot groups g0=hi, g1=lo, g2=hi, g3=0
    short8v bq[4];
    #pragma unroll
    for (int qt = 0; qt < 4; ++qt) {
        if (g == 3) { short8v zz = {0,0,0,0,0,0,0,0}; bq[qt] = zz; }
        else bq[qt] = *(const short8v*)(qb + (size_t)(q0 + qt * 16 + cl) * 16 + ((g == 1) ? 8 : 0));
    }

    // A(K) fragment plane: g0,g1 -> hi; g2,g3 -> lo (g3's B slots are 0)
    const int koff = (g >> 1) * 8;
    const unsigned short* kp = kb + kq * 4096 + cl * 16 + koff;

    // V A-fragment gather pointer (one b128 per superstep)
    const unsigned int* ap;
    int astr;
    {
        const size_t vb = (size_t)bh * 512 + kq * 128 + g * 4;
        if (cl == 0)      { ap = Vsh + vb; astr = 16; }
        else if (cl == 2) { ap = Vsl + vb; astr = 16; }
        else if (cl == 1) { ap = obuf;     astr = 0;  }
        else              { ap = obuf + 4; astr = 0;  }
    }

    const float4v c0 = {0.f, 0.f, 0.f, 0.f};
    float4v acc[4];
    #pragma unroll
    for (int qt = 0; qt < 4; ++qt) acc[qt] = c0;

    short8v k0c = *(const short8v*)kp;
    short8v k1c = *(const short8v*)(kp + 256);
    uint4v  auc = *(const uint4v*)ap;

    #pragma unroll
    for (int ss = 0; ss < 8; ++ss) {
        short8v k0n, k1n; uint4v aun;
        if (ss < 7) {
            k0n = *(const short8v*)(kp + 512);
            k1n = *(const short8v*)(kp + 768);
            aun = *(const uint4v*)(ap + astr);
        }
        kp += 512; ap += astr;
        const short8v af = __builtin_bit_cast(short8v, auc);
        #pragma unroll
        for (int qt = 0; qt < 4; ++qt) {
            float4v s0 = __builtin_amdgcn_mfma_f32_16x16x32_bf16(k0c, bq[qt], c0, 0, 0, 0);
            float4v s1 = __builtin_amdgcn_mfma_f32_16x16x32_bf16(k1c, bq[qt], c0, 0, 0, 0);
            float p00 = __builtin_amdgcn_exp2f(s0[0]);
            float p01 = __builtin_amdgcn_exp2f(s0[1]);
            float p02 = __builtin_amdgcn_exp2f(s0[2]);
            float p03 = __builtin_amdgcn_exp2f(s0[3]);
            float p10 = __builtin_amdgcn_exp2f(s1[0]);
            float p11 = __builtin_amdgcn_exp2f(s1[1]);
            float p12 = __builtin_amdgcn_exp2f(s1[2]);
            float p13 = __builtin_amdgcn_exp2f(s1[3]);
            unsigned int pk0 = __builtin_amdgcn_perm(__float_as_uint(p01), __float_as_uint(p00), 0x07060302u);
            unsigned int pk1 = __builtin_amdgcn_perm(__float_as_uint(p03), __float_as_uint(p02), 0x07060302u);
            unsigned int pk2 = __builtin_amdgcn_perm(__float_as_uint(p11), __float_as_uint(p10), 0x07060302u);
            unsigned int pk3 = __builtin_amdgcn_perm(__float_as_uint(p13), __float_as_uint(p12), 0x07060302u);
            uint4v pu = {pk0, pk1, pk2, pk3};
            acc[qt] = __builtin_amdgcn_mfma_f32_16x16x32_bf16(af, __builtin_bit_cast(short8v, pu), acc[qt], 0, 0, 0);
        }
        if (ss < 7) { k0c = k0n; k1c = k1n; auc = aun; }
    }

    if (g == 0) {
        #pragma unroll
        for (int qt = 0; qt < 4; ++qt) {
            const int row = q0 + qt * 16 + cl;
            float2 pr;
            pr.x = acc[qt][0] + acc[qt][2];   // numerator (v_hi + v_lo parts)
            pr.y = acc[qt][1];                // denominator
            part[(size_t)(kq * 256 + bh) * SEQ + row] = pr;
        }
    }
}

// ---------------------------------------------------------------------------
// Merge split-K quarters + positional embedding. h-fastest coalesced out.
// ---------------------------------------------------------------------------
__global__ __launch_bounds__(256)
void merge_kernel(const float2* __restrict__ part, float* __restrict__ out)
{
    const int tid = blockIdx.x * 256 + threadIdx.x;  // = (b*1024+q)*64+h
    const int h = tid & 63;
    const int q = (tid >> 6) & 1023;
    const int b = tid >> 16;
    const int bh = (b << 6) + h;
    float num = 0.f, den = 0.f;
    #pragma unroll
    for (int kq = 0; kq < 4; ++kq) {
        float2 p = part[(size_t)(kq * 256 + bh) * SEQ + q];
        num += p.x; den += p.y;
    }
    const float fr = __builtin_amdgcn_exp2f((float)(h & 31) * -0.4152410118609203f);
    const float pe = (h < 32) ? cosf((float)q * fr) : sinf((float)q * fr);
    out[tid] = num / den + pe;
}

// ---------------------------------------------------------------------------
extern "C" void kernel_launch(void* const* d_in, const int* in_sizes, int n_in,
                              void* d_out, int out_size, void* d_ws, size_t ws_size,
                              hipStream_t stream)
{
    const float* x  = (const float*)d_in[0];
    const float* Wq = (const float*)d_in[1];
    const float* bq = (const float*)d_in[2];
    const float* Wk = (const float*)d_in[3];
    const float* bk = (const float*)d_in[4];
    const float* Wv = (const float*)d_in[5];
    const float* bv = (const float*)d_in[6];
    float* out = (float*)d_out;

    // ws layout:
    //   Qpk 8.39MB | Kpk 8.39MB | Vsh .52 | Vsl .52 | obuf 256B |
    //   Xhi 4.19MB | Xlo 4.19MB  (part[8MB] aliases Xhi: X dead after proj) |
    //   W planes 2.23MB
    unsigned short* Qpk = (unsigned short*)d_ws;
    unsigned short* Kpk = Qpk + (size_t)BATCH * NH * SEQ * 16;
    unsigned int* Vsh = (unsigned int*)(Kpk + (size_t)BATCH * NH * SEQ * 16);
    unsigned int* Vsl = Vsh + (size_t)BATCH * NH * (SEQ / 2);
    unsigned int* obuf = Vsl + (size_t)BATCH * NH * (SEQ / 2);
    unsigned short* Xhi = (unsigned short*)(obuf + 64);
    unsigned short* Xlo = Xhi + (size_t)BATCH * SEQ * DIN;
    float2* part = (float2*)Xhi;   // aliases X planes
    unsigned short* WhiQ = Xlo + (size_t)BATCH * SEQ * DIN;
    unsigned short* WloQ = WhiQ + (size_t)DIN * DKQ;
    unsigned short* WhiK = WloQ + (size_t)DIN * DKQ;
    unsigned short* WloK = WhiK + (size_t)DIN * DKQ;
    unsigned short* WhiV = WloK + (size_t)DIN * DKQ;
    unsigned short* WloV = WhiV + (size_t)DIN * DV;

    pack_x<<<dim3((BATCH * SEQ * DIN) / (8 * 256)), 256, 0, stream>>>(x, Xhi, Xlo, obuf);
    transpose_w<<<dim3(16, 16, 3), dim3(32, 8), 0, stream>>>(
        Wq, Wk, Wv, WhiQ, WloQ, WhiK, WloK, WhiV, WloV);
    proj_kernel<<<dim3(4, 32, 3), 512, 0, stream>>>(
        Xhi, Xlo, WhiQ, WloQ, bq, WhiK, WloK, bk, WhiV, WloV, bv, Qpk, Kpk, Vsh, Vsl);
    attn_kernel<<<dim3(256, 16), 256, 0, stream>>>(Qpk, Kpk, Vsh, Vsl, obuf, part);
    merge_kernel<<<dim3((BATCH * SEQ * DV) / 256), 256, 0, stream>>>(part, out);
}